// Round 3
// 940.786 us; speedup vs baseline: 1.1062x; 1.1062x over previous
//
#include <hip/hip_runtime.h>

// ---------------------------------------------------------------------------
// TransformerBlock: MHA -> LN1 -> top-2 MoE -> LN3   (MI355X / gfx950)
// All heavy GEMMs: bf16 MFMA 16x16x32, fp32 accumulate.
// R6 (bisect after two container failures on R5):
//   - gemm_qkv / gemm_moe: R4's proven reg-staged mainloop + T14 register
//     prefetch of the next K-step (issue loads before the barrier).
//   - gemm_oproj ONLY: R5's global_load_lds mainloop (attribution probe /
//     in-run A/B vs reg-staged at identical 1024^3 shape).
//   - flash_attn: 64-row q-tiles, grid (32,32) = 4 blocks/CU (R0 showed
//     22% occupancy grid limit with all pipes idle).
// ---------------------------------------------------------------------------

typedef __attribute__((ext_vector_type(8))) short bf16x8;   // 8 bf16 = 4 VGPR
typedef __attribute__((ext_vector_type(4))) float f32x4;    // MFMA acc

typedef const __attribute__((address_space(1))) unsigned int* gas_p;
typedef __attribute__((address_space(3))) unsigned int* las_p;

#define T_TOK 4096
#define DMODEL 1024
#define DFF 4096
#define NEXP 8
#define SEQ 2048
#define NSLOT 8192          // T * top_k
#define NSLOT_PAD (8192+256)
#define LDS_STRIDE 72       // reg-staged GEMM + attn tiles: 64 + 8 pad

__device__ __forceinline__ ushort f2b(float f) {            // fp32 -> bf16 RNE
  union { float f; unsigned u; } v; v.f = f;
  unsigned r = (v.u + 0x7FFFu + ((v.u >> 16) & 1u)) >> 16;
  return (ushort)r;
}
__device__ __forceinline__ float b2f(ushort u) {
  union { unsigned u; float f; } v; v.u = ((unsigned)u) << 16; return v.f;
}

// async global->LDS, 16B per lane; LDS dest = wave-uniform base + lane*16
__device__ __forceinline__ void gload16(const ushort* g, ushort* lds) {
  __builtin_amdgcn_global_load_lds((gas_p)g, (las_p)lds, 16, 0, 0);
}

// --------------------------- small utility kernels -------------------------

__global__ __launch_bounds__(256) void cvt_bf16(const float* __restrict__ in,
                                                ushort* __restrict__ out, long n,
                                                int* __restrict__ cnt) {
  if (blockIdx.x == 0 && threadIdx.x < 16) cnt[threadIdx.x] = 0;
  long i = ((long)blockIdx.x * 256 + threadIdx.x) * 4;
  if (i >= n) return;
  float4 v = *(const float4*)(in + i);
  ushort4 o; o.x = f2b(v.x); o.y = f2b(v.y); o.z = f2b(v.z); o.w = f2b(v.w);
  *(ushort4*)(out + i) = o;
}

// out[z][c][r] = bf16(in[z][r][c]);  R,C multiples of 64
__global__ __launch_bounds__(256) void wtrans(const float* __restrict__ in,
                                              ushort* __restrict__ out, int R, int C) {
  __shared__ float tile[64][65];
  long base = (long)blockIdx.z * R * C;
  int r0 = blockIdx.y * 64, c0 = blockIdx.x * 64;
  int t = threadIdx.x;
  int tr = t >> 4, tc = (t & 15) * 4;
#pragma unroll
  for (int i = 0; i < 4; i++) {
    float4 v = *(const float4*)(in + base + (long)(r0 + tr + i * 16) * C + c0 + tc);
    tile[tr + i * 16][tc + 0] = v.x; tile[tr + i * 16][tc + 1] = v.y;
    tile[tr + i * 16][tc + 2] = v.z; tile[tr + i * 16][tc + 3] = v.w;
  }
  __syncthreads();
#pragma unroll
  for (int i = 0; i < 4; i++) {
    int c = tr + i * 16, r = tc;
    ushort4 o;
    o.x = f2b(tile[r + 0][c]); o.y = f2b(tile[r + 1][c]);
    o.z = f2b(tile[r + 2][c]); o.w = f2b(tile[r + 3][c]);
    *(ushort4*)(out + base + (long)(c0 + c) * R + r0 + r) = o;
  }
}

// V [B*S][1024] bf16 -> Vt [bh][64][2048] bf16
__global__ __launch_bounds__(256) void vtrans(const ushort* __restrict__ Vb,
                                              ushort* __restrict__ Vt) {
  __shared__ ushort tile[64 * 72];
  int s0 = blockIdx.x * 64, h = blockIdx.y, b = blockIdx.z;
  int t = threadIdx.x;
  int chunk = t & 7;
#pragma unroll
  for (int rep = 0; rep < 2; rep++) {
    int row = (t >> 3) + rep * 32;
    *(uint4*)(tile + row * 72 + chunk * 8) =
        *(const uint4*)(Vb + (long)(b * SEQ + s0 + row) * DMODEL + h * 64 + chunk * 8);
  }
  __syncthreads();
#pragma unroll
  for (int rep = 0; rep < 2; rep++) {
    int idx = rep * 256 + t; int d = idx >> 3; int sc = (idx & 7) * 8;
    union { ushort u[8]; uint4 v; } tmp;
#pragma unroll
    for (int j = 0; j < 8; j++) tmp.u[j] = tile[(sc + j) * 72 + d];
    *(uint4*)(Vt + ((long)(b * 16 + h) * 64 + d) * SEQ + s0 + sc) = tmp.v;
  }
}

// ------------------- BK=64 GEMM mainloop, reg-staged (R4) ------------------
// 128x128 tile, 4 waves, BK=64, LDS stride 72. Per iter: ds_write the
// current K-step from registers, then immediately issue the NEXT K-step's
// global loads (T14 split: latency hides under barrier + MFMA compute).

__device__ __forceinline__ void mainloop64_reg(
    const ushort* a0, const ushort* a1, const ushort* a2, const ushort* a3,
    const ushort* b0, const ushort* b1, const ushort* b2, const ushort* b3,
    ushort* As, ushort* Bs, int K,
    int wm, int wn, int quad, int l15, f32x4 acc[4][4]) {
  const int t = threadIdx.x;
  const int rA = t >> 3, c8 = (t & 7) * 8;
  uint4 ra0 = *(const uint4*)a0, ra1 = *(const uint4*)a1;
  uint4 ra2 = *(const uint4*)a2, ra3 = *(const uint4*)a3;
  uint4 rb0 = *(const uint4*)b0, rb1 = *(const uint4*)b1;
  uint4 rb2 = *(const uint4*)b2, rb3 = *(const uint4*)b3;
  for (int k0 = 0; k0 < K; k0 += 64) {
    __syncthreads();
    *(uint4*)(As + (rA +  0) * LDS_STRIDE + c8) = ra0;
    *(uint4*)(As + (rA + 32) * LDS_STRIDE + c8) = ra1;
    *(uint4*)(As + (rA + 64) * LDS_STRIDE + c8) = ra2;
    *(uint4*)(As + (rA + 96) * LDS_STRIDE + c8) = ra3;
    *(uint4*)(Bs + (rA +  0) * LDS_STRIDE + c8) = rb0;
    *(uint4*)(Bs + (rA + 32) * LDS_STRIDE + c8) = rb1;
    *(uint4*)(Bs + (rA + 64) * LDS_STRIDE + c8) = rb2;
    *(uint4*)(Bs + (rA + 96) * LDS_STRIDE + c8) = rb3;
    int kn = k0 + 64;
    if (kn < K) {   // prefetch next K-step; in flight across barrier+MFMA
      ra0 = *(const uint4*)(a0 + kn); ra1 = *(const uint4*)(a1 + kn);
      ra2 = *(const uint4*)(a2 + kn); ra3 = *(const uint4*)(a3 + kn);
      rb0 = *(const uint4*)(b0 + kn); rb1 = *(const uint4*)(b1 + kn);
      rb2 = *(const uint4*)(b2 + kn); rb3 = *(const uint4*)(b3 + kn);
    }
    __syncthreads();
#pragma unroll
    for (int kk = 0; kk < 64; kk += 32) {
      bf16x8 af[4], bfr[4];
#pragma unroll
      for (int i = 0; i < 4; i++)
        af[i] = *(const bf16x8*)(As + (wm + i * 16 + l15) * LDS_STRIDE + kk + quad * 8);
#pragma unroll
      for (int i = 0; i < 4; i++)
        bfr[i] = *(const bf16x8*)(Bs + (wn + i * 16 + l15) * LDS_STRIDE + kk + quad * 8);
#pragma unroll
      for (int mi = 0; mi < 4; mi++)
#pragma unroll
        for (int ni = 0; ni < 4; ni++)
          acc[mi][ni] = __builtin_amdgcn_mfma_f32_16x16x32_bf16(af[mi], bfr[ni], acc[mi][ni], 0, 0, 0);
    }
  }
}

// ------------- BK=64 GEMM mainloop, global_load_lds (probe) ----------------
// Same tile; staging via global_load_lds width 16, linear LDS stride 64.
// Wave w's lane l lands at LDS row w*8+(l>>3), col (l&7)*8 -- matches the
// per-thread global pointers (rA = t>>3, c8 = (t&7)*8).

__device__ __forceinline__ void mainloop64_lds(
    const ushort* a0, const ushort* a1, const ushort* a2, const ushort* a3,
    const ushort* b0, const ushort* b1, const ushort* b2, const ushort* b3,
    ushort* As, ushort* Bs, int K,
    int wm, int wn, int quad, int l15, f32x4 acc[4][4]) {
  const int w = threadIdx.x >> 6;
  ushort* Asw = As + w * 8 * 64;
  ushort* Bsw = Bs + w * 8 * 64;
  for (int k0 = 0; k0 < K; k0 += 64) {
    __syncthreads();
    gload16(a0 + k0, Asw + 0 * 64);
    gload16(a1 + k0, Asw + 32 * 64);
    gload16(a2 + k0, Asw + 64 * 64);
    gload16(a3 + k0, Asw + 96 * 64);
    gload16(b0 + k0, Bsw + 0 * 64);
    gload16(b1 + k0, Bsw + 32 * 64);
    gload16(b2 + k0, Bsw + 64 * 64);
    gload16(b3 + k0, Bsw + 96 * 64);
    __syncthreads();
#pragma unroll
    for (int kk = 0; kk < 64; kk += 32) {
      bf16x8 af[4], bfr[4];
#pragma unroll
      for (int i = 0; i < 4; i++)
        af[i] = *(const bf16x8*)(As + (wm + i * 16 + l15) * 64 + kk + quad * 8);
#pragma unroll
      for (int i = 0; i < 4; i++)
        bfr[i] = *(const bf16x8*)(Bs + (wn + i * 16 + l15) * 64 + kk + quad * 8);
#pragma unroll
      for (int mi = 0; mi < 4; mi++)
#pragma unroll
        for (int ni = 0; ni < 4; ni++)
          acc[mi][ni] = __builtin_amdgcn_mfma_f32_16x16x32_bf16(af[mi], bfr[ni], acc[mi][ni], 0, 0, 0);
    }
  }
}

// QKV: one launch, z selects {Q,K,V}; Q epilogue folds 1/sqrt(dk)=0.125
// grid (n=8, m=32, 3)
__global__ __launch_bounds__(256, 2) void gemm_qkv(
    const ushort* __restrict__ A,
    const ushort* __restrict__ BtQ, const ushort* __restrict__ BtK, const ushort* __restrict__ BtV,
    const float* __restrict__ bq, const float* __restrict__ bk, const float* __restrict__ bv,
    ushort* __restrict__ oq, ushort* __restrict__ ok, ushort* __restrict__ ov) {
  __shared__ ushort As[128 * LDS_STRIDE], Bs[128 * LDS_STRIDE];
  int z = blockIdx.z;
  const ushort* Bt = (z == 0) ? BtQ : (z == 1) ? BtK : BtV;
  const float* bias = (z == 0) ? bq : (z == 1) ? bk : bv;
  ushort* outp = (z == 0) ? oq : (z == 1) ? ok : ov;
  float scale = (z == 0) ? 0.125f : 1.0f;
  const int m0 = blockIdx.y * 128, n0 = blockIdx.x * 128;
  const int t = threadIdx.x, w = t >> 6, lane = t & 63, quad = lane >> 4, l15 = lane & 15;
  const int wm = (w >> 1) * 64, wn = (w & 1) * 64;
  const int rA = t >> 3, c8 = (t & 7) * 8;
  const ushort* a0 = A + (long)(m0 + rA) * DMODEL + c8;
  const ushort* b0 = Bt + (long)(n0 + rA) * DMODEL + c8;
  f32x4 acc[4][4];
  f32x4 zv = {0.f, 0.f, 0.f, 0.f};
  for (int i = 0; i < 4; i++) for (int j = 0; j < 4; j++) acc[i][j] = zv;
  mainloop64_reg(a0, a0 + 32 * DMODEL, a0 + 64 * DMODEL, a0 + 96 * DMODEL,
                 b0, b0 + 32 * DMODEL, b0 + 64 * DMODEL, b0 + 96 * DMODEL,
                 As, Bs, DMODEL, wm, wn, quad, l15, acc);
#pragma unroll
  for (int mi = 0; mi < 4; mi++)
#pragma unroll
    for (int ni = 0; ni < 4; ni++) {
      int row = m0 + wm + mi * 16 + quad * 4;
      int col = n0 + wn + ni * 16 + l15;
      float bb = bias[col];
#pragma unroll
      for (int r = 0; r < 4; r++)
        outp[(long)(row + r) * DMODEL + col] = f2b((acc[mi][ni][r] + bb) * scale);
    }
}

// O projection: fp32 out = acc + bo + residual(x); grid (8, 32)
// PROBE: global_load_lds staging (linear LDS stride 64).
__global__ __launch_bounds__(256, 2) void gemm_oproj(
    const ushort* __restrict__ A, const ushort* __restrict__ Bt,
    const float* __restrict__ bias, const float* __restrict__ resid,
    float* __restrict__ outf) {
  __shared__ ushort As[128 * 64], Bs[128 * 64];
  const int m0 = blockIdx.y * 128, n0 = blockIdx.x * 128;
  const int t = threadIdx.x, w = t >> 6, lane = t & 63, quad = lane >> 4, l15 = lane & 15;
  const int wm = (w >> 1) * 64, wn = (w & 1) * 64;
  const int rA = t >> 3, c8 = (t & 7) * 8;
  const ushort* a0 = A + (long)(m0 + rA) * DMODEL + c8;
  const ushort* b0 = Bt + (long)(n0 + rA) * DMODEL + c8;
  f32x4 acc[4][4];
  f32x4 zv = {0.f, 0.f, 0.f, 0.f};
  for (int i = 0; i < 4; i++) for (int j = 0; j < 4; j++) acc[i][j] = zv;
  mainloop64_lds(a0, a0 + 32 * DMODEL, a0 + 64 * DMODEL, a0 + 96 * DMODEL,
                 b0, b0 + 32 * DMODEL, b0 + 64 * DMODEL, b0 + 96 * DMODEL,
                 As, Bs, DMODEL, wm, wn, quad, l15, acc);
#pragma unroll
  for (int mi = 0; mi < 4; mi++)
#pragma unroll
    for (int ni = 0; ni < 4; ni++) {
      int row = m0 + wm + mi * 16 + quad * 4;
      int col = n0 + wn + ni * 16 + l15;
      float bb = bias[col];
#pragma unroll
      for (int r = 0; r < 4; r++) {
        long idx = (long)(row + r) * DMODEL + col;
        outf[idx] = acc[mi][ni][r] + bb + resid[idx];
      }
    }
}

// Grouped MoE GEMM, 128x128 tile, BK=64. grid (n-blocks, 72): weight-sharing
// blocks differ by gridDim.x (32 or 8, % 8 == 0) -> same XCD.
// mode 2: x1b gathered -> act -> abuf[slot][F];  mode 3: abuf -> ybuf[slot][D]
__global__ __launch_bounds__(256, 2) void gemm_moe(
    int mode, const ushort* __restrict__ Abase, const int* __restrict__ slot_token,
    const ushort* __restrict__ WT, const float* __restrict__ biasE,
    ushort* __restrict__ outp, int K, int N,
    const int* __restrict__ tab_e, const int* __restrict__ tab_r0,
    const int* __restrict__ tab_end, const int* __restrict__ nmb) {
  int mb = blockIdx.y;
  if (mb >= *nmb) return;
  __shared__ ushort As[128 * LDS_STRIDE], Bs[128 * LDS_STRIDE];
  int e = tab_e[mb], r0 = tab_r0[mb], rend = tab_end[mb];
  const int t = threadIdx.x, w = t >> 6, lane = t & 63, quad = lane >> 4, l15 = lane & 15;
  const int wm = (w >> 1) * 64, wn = (w & 1) * 64;
  const int rA = t >> 3, c8 = (t & 7) * 8;
  const int n0 = blockIdx.x * 128;
  const ushort* ap[4];
#pragma unroll
  for (int j = 0; j < 4; j++) {
    int r = r0 + rA + 32 * j;
    if (mode == 2) {
      int ci = r < rend ? r : rend - 1;
      ap[j] = Abase + (long)slot_token[ci] * K + c8;
    } else {
      ap[j] = Abase + (long)r * K + c8;   // rows past rend read pad; store-masked
    }
  }
  const ushort* Bt = WT + (long)e * K * N;
  const ushort* b0 = Bt + (long)(n0 + rA) * K + c8;
  f32x4 acc[4][4];
  f32x4 zv = {0.f, 0.f, 0.f, 0.f};
  for (int i = 0; i < 4; i++) for (int j = 0; j < 4; j++) acc[i][j] = zv;
  mainloop64_reg(ap[0], ap[1], ap[2], ap[3],
                 b0, b0 + (long)32 * K, b0 + (long)64 * K, b0 + (long)96 * K,
                 As, Bs, K, wm, wn, quad, l15, acc);
  const float* bb = biasE + (long)e * N;
  bool odd = (e & 1) != 0;
#pragma unroll
  for (int mi = 0; mi < 4; mi++)
#pragma unroll
    for (int ni = 0; ni < 4; ni++) {
      int col = n0 + wn + ni * 16 + l15;
      float bv = bb[col];
#pragma unroll
      for (int r = 0; r < 4; r++) {
        int slot = r0 + wm + mi * 16 + quad * 4 + r;
        if (slot < rend) {
          float v = acc[mi][ni][r] + bv;
          if (mode == 2)
            v = odd ? (v / (1.f + __expf(-v)))                       // silu
                    : (0.5f * v * (1.f + erff(v * 0.70710678118f))); // exact gelu
          outp[(long)slot * N + col] = f2b(v);
        }
      }
    }
}

// --------------------------- flash attention -------------------------------
// grid (32 q-tiles, 32 bh). 64 q rows/block, kv tiles of 64. 4 waves, each
// owns 16 q rows fully -> softmax state is wave-private. 4 blocks/CU.
__global__ __launch_bounds__(256, 4) void flash_attn(
    const ushort* __restrict__ Qb, const ushort* __restrict__ Kb,
    const ushort* __restrict__ Vt, ushort* __restrict__ ctx) {
  __shared__ ushort QP[64 * 72];    // Q staging, then P (per-wave-private rows)
  __shared__ ushort Ks[64 * 72];
  __shared__ ushort Vs[64 * 72];    // Vt tile: [d][kv]
  const int t = threadIdx.x, w = t >> 6, lane = t & 63, quad = lane >> 4, l15 = lane & 15;
  const int q0 = blockIdx.x * 64, bh = blockIdx.y, b = bh >> 4, h = bh & 15;
  {
    int chunk = t & 7, hcol = h * 64 + chunk * 8;
#pragma unroll
    for (int rep = 0; rep < 2; rep++) {
      int row = (t >> 3) + rep * 32;
      *(uint4*)(QP + row * 72 + chunk * 8) =
          *(const uint4*)(Qb + (long)(b * SEQ + q0 + row) * DMODEL + hcol);
    }
  }
  __syncthreads();
  bf16x8 qf[2];
#pragma unroll
  for (int kc = 0; kc < 2; kc++)
    qf[kc] = *(const bf16x8*)(QP + (w * 16 + l15) * 72 + kc * 32 + quad * 8);

  f32x4 O[4];
  f32x4 zv = {0.f, 0.f, 0.f, 0.f};
  float m_r[4], l_r[4];
#pragma unroll
  for (int i = 0; i < 4; i++) { O[i] = zv; m_r[i] = -1e30f; l_r[i] = 0.f; }

  for (int kv0 = 0; kv0 < SEQ; kv0 += 64) {
    __syncthreads();
    {
      int chunk = t & 7, hcol = h * 64 + chunk * 8;
#pragma unroll
      for (int rep = 0; rep < 2; rep++) {
        int row = (t >> 3) + rep * 32;
        *(uint4*)(Ks + row * 72 + chunk * 8) =
            *(const uint4*)(Kb + (long)(b * SEQ + kv0 + row) * DMODEL + hcol);
        *(uint4*)(Vs + row * 72 + chunk * 8) =
            *(const uint4*)(Vt + ((long)bh * 64 + row) * SEQ + kv0 + chunk * 8);
      }
    }
    __syncthreads();
    // S = Q K^T  (Q pre-scaled by 0.125)
    f32x4 S[4];
#pragma unroll
    for (int ct = 0; ct < 4; ct++) {
      bf16x8 kf0 = *(const bf16x8*)(Ks + (ct * 16 + l15) * 72 + quad * 8);
      bf16x8 kf1 = *(const bf16x8*)(Ks + (ct * 16 + l15) * 72 + 32 + quad * 8);
      f32x4 s = zv;
      s = __builtin_amdgcn_mfma_f32_16x16x32_bf16(qf[0], kf0, s, 0, 0, 0);
      s = __builtin_amdgcn_mfma_f32_16x16x32_bf16(qf[1], kf1, s, 0, 0, 0);
      S[ct] = s;
    }
    // online softmax (rows wave-private; 16-lane groups share a row)
#pragma unroll
    for (int r = 0; r < 4; r++) {
      float mx = fmaxf(fmaxf(S[0][r], S[1][r]), fmaxf(S[2][r], S[3][r]));
      mx = fmaxf(mx, __shfl_xor(mx, 1));
      mx = fmaxf(mx, __shfl_xor(mx, 2));
      mx = fmaxf(mx, __shfl_xor(mx, 4));
      mx = fmaxf(mx, __shfl_xor(mx, 8));
      float nm = fmaxf(m_r[r], mx);
      float alpha = __expf(m_r[r] - nm);
      m_r[r] = nm;
      float p0 = __expf(S[0][r] - nm), p1 = __expf(S[1][r] - nm);
      float p2 = __expf(S[2][r] - nm), p3 = __expf(S[3][r] - nm);
      float rs = p0 + p1 + p2 + p3;
      rs += __shfl_xor(rs, 1); rs += __shfl_xor(rs, 2);
      rs += __shfl_xor(rs, 4); rs += __shfl_xor(rs, 8);
      l_r[r] = l_r[r] * alpha + rs;
#pragma unroll
      for (int dt = 0; dt < 4; dt++) O[dt][r] *= alpha;
      int prow = (w * 16 + quad * 4 + r) * 72;
      QP[prow + 0 * 16 + l15] = f2b(p0);
      QP[prow + 1 * 16 + l15] = f2b(p1);
      QP[prow + 2 * 16 + l15] = f2b(p2);
      QP[prow + 3 * 16 + l15] = f2b(p3);
    }
    // O += P V   (P rows are this wave's own -> in-wave LDS RAW, no barrier)
    bf16x8 pf[2];
#pragma unroll
    for (int ks = 0; ks < 2; ks++)
      pf[ks] = *(const bf16x8*)(QP + (w * 16 + l15) * 72 + ks * 32 + quad * 8);
#pragma unroll
    for (int dt = 0; dt < 4; dt++) {
      bf16x8 vf0 = *(const bf16x8*)(Vs + (dt * 16 + l15) * 72 + quad * 8);
      bf16x8 vf1 = *(const bf16x8*)(Vs + (dt * 16 + l15) * 72 + 32 + quad * 8);
      O[dt] = __builtin_amdgcn_mfma_f32_16x16x32_bf16(pf[0], vf0, O[dt], 0, 0, 0);
      O[dt] = __builtin_amdgcn_mfma_f32_16x16x32_bf16(pf[1], vf1, O[dt], 0, 0, 0);
    }
  }
#pragma unroll
  for (int r = 0; r < 4; r++) {
    float inv = 1.f / l_r[r];
    int row = b * SEQ + q0 + w * 16 + quad * 4 + r;
#pragma unroll
    for (int dt = 0; dt < 4; dt++)
      ctx[(long)row * DMODEL + h * 64 + dt * 16 + l15] = f2b(O[dt][r] * inv);
  }
}

// --------------------------- LN1 + gate (fused) ----------------------------

__device__ __forceinline__ float block_sum(float v, float* red) {
#pragma unroll
  for (int off = 32; off; off >>= 1) v += __shfl_down(v, off);
  int w = threadIdx.x >> 6;
  __syncthreads();
  if ((threadIdx.x & 63) == 0) red[w] = v;
  __syncthreads();
  return red[0] + red[1] + red[2] + red[3];
}

__global__ __launch_bounds__(256) void ln1_gate(const float* __restrict__ in,
    const float* __restrict__ g, const float* __restrict__ bb,
    const float* __restrict__ gw, const float* __restrict__ gb,
    float* __restrict__ outf, ushort* __restrict__ outh,
    int* __restrict__ top2i, float* __restrict__ top2s, int* __restrict__ cnt) {
  __shared__ float red[4];
  __shared__ float red8[4][8];
  long row = blockIdx.x;
  int t = threadIdx.x, w = t >> 6, lane = t & 63;
  float4 v = *(const float4*)(in + row * DMODEL + t * 4);
  float s = block_sum(v.x + v.y + v.z + v.w, red);
  float mean = s * (1.0f / DMODEL);
  float d0 = v.x - mean, d1 = v.y - mean, d2 = v.z - mean, d3 = v.w - mean;
  float sq = block_sum(d0 * d0 + d1 * d1 + d2 * d2 + d3 * d3, red);
  float rstd = rsqrtf(sq * (1.0f / DMODEL) + 1e-5f);
  float4 gg = *(const float4*)(g + t * 4);
  float4 bv = *(const float4*)(bb + t * 4);
  float o0 = d0 * rstd * gg.x + bv.x, o1 = d1 * rstd * gg.y + bv.y;
  float o2 = d2 * rstd * gg.z + bv.z, o3 = d3 * rstd * gg.w + bv.w;
  float4 of; of.x = o0; of.y = o1; of.z = o2; of.w = o3;
  *(float4*)(outf + row * DMODEL + t * 4) = of;
  ushort4 oh; oh.x = f2b(o0); oh.y = f2b(o1); oh.z = f2b(o2); oh.w = f2b(o3);
  *(ushort4*)(outh + row * DMODEL + t * 4) = oh;
  // gate logits: a[e] = sum_col o_col * gw[col][e]
  float a[8];
  {
    const float* gr = gw + (long)(t * 4) * 8;
    float4 w0 = *(const float4*)(gr +  0), w1 = *(const float4*)(gr +  4);
    float4 w2 = *(const float4*)(gr +  8), w3 = *(const float4*)(gr + 12);
    float4 w4 = *(const float4*)(gr + 16), w5 = *(const float4*)(gr + 20);
    float4 w6 = *(const float4*)(gr + 24), w7 = *(const float4*)(gr + 28);
    a[0] = o0 * w0.x + o1 * w2.x + o2 * w4.x + o3 * w6.x;
    a[1] = o0 * w0.y + o1 * w2.y + o2 * w4.y + o3 * w6.y;
    a[2] = o0 * w0.z + o1 * w2.z + o2 * w4.z + o3 * w6.z;
    a[3] = o0 * w0.w + o1 * w2.w + o2 * w4.w + o3 * w6.w;
    a[4] = o0 * w1.x + o1 * w3.x + o2 * w5.x + o3 * w7.x;
    a[5] = o0 * w1.y + o1 * w3.y + o2 * w5.y + o3 * w7.y;
    a[6] = o0 * w1.z + o1 * w3.z + o2 * w5.z + o3 * w7.z;
    a[7] = o0 * w1.w + o1 * w3.w + o2 * w5.w + o3 * w7.w;
  }
#pragma unroll
  for (int off = 32; off; off >>= 1)
#pragma unroll
    for (int e = 0; e < 8; e++) a[e] += __shfl_down(a[e], off);
  if (lane == 0) {
#pragma unroll
    for (int e = 0; e < 8; e++) red8[w][e] = a[e];
  }
  __syncthreads();
  if (t == 0) {
    float L[8];
#pragma unroll
    for (int e = 0; e < 8; e++)
      L[e] = red8[0][e] + red8[1][e] + red8[2][e] + red8[3][e] + gb[e];
    int e0 = 0; float v0 = L[0];
#pragma unroll
    for (int e = 1; e < 8; e++) if (L[e] > v0) { v0 = L[e]; e0 = e; }
    int e1 = -1; float v1 = -1e30f;
#pragma unroll
    for (int e = 0; e < 8; e++) if (e != e0 && L[e] > v1) { v1 = L[e]; e1 = e; }
    float q = __expf(v1 - v0);
    float inv = 1.f / (1.f + q);
    top2i[2 * row] = e0; top2i[2 * row + 1] = e1;
    top2s[2 * row] = inv; top2s[2 * row + 1] = q * inv;
    atomicAdd(&cnt[e0], 1); atomicAdd(&cnt[e1], 1);
  }
}

__global__ void build_tables(const int* __restrict__ cnt, int* __restrict__ off,
                             int* __restrict__ tab_e, int* __restrict__ tab_r0,
                             int* __restrict__ tab_end, int* __restrict__ nmb) {
  if (threadIdx.x == 0 && blockIdx.x == 0) {
    int o = 0, m = 0;
    for (int e = 0; e < NEXP; e++) {
      off[e] = o;
      int c = cnt[e];
      for (int j = 0; j * 128 < c; j++) { tab_e[m] = e; tab_r0[m] = o + j * 128; tab_end[m] = o + c; m++; }
      o += c;
    }
    off[NEXP] = o;
    *nmb = m;
  }
}

__global__ __launch_bounds__(256) void scatter_slots(const int* __restrict__ top2i,
    const float* __restrict__ top2s, const int* __restrict__ off, int* __restrict__ fill,
    int* __restrict__ slot_token, float* __restrict__ slot_scale, int* __restrict__ pos) {
  int t = blockIdx.x * 256 + threadIdx.x;
  if (t >= T_TOK) return;
#pragma unroll
  for (int k = 0; k < 2; k++) {
    int e = top2i[2 * t + k];
    int p = off[e] + atomicAdd(&fill[e], 1);
    slot_token[p] = t;
    slot_scale[p] = top2s[2 * t + k];
    pos[2 * t + k] = p;
  }
}

__global__ __launch_bounds__(256) void combine_ln3(const float* __restrict__ x1,
    const ushort* __restrict__ ybuf, const int* __restrict__ pos,
    const float* __restrict__ sscale, const float* __restrict__ g,
    const float* __restrict__ bb, float* __restrict__ outp) {
  __shared__ float red[4];
  long row = blockIdx.x;
  int t = threadIdx.x;
  int p0 = pos[2 * row], p1 = pos[2 * row + 1];
  float s0 = sscale[p0], s1 = sscale[p1];
  float4 xv = *(const float4*)(x1 + row * DMODEL + t * 4);
  ushort4 y0 = *(const ushort4*)(ybuf + (long)p0 * DMODEL + t * 4);
  ushort4 y1 = *(const ushort4*)(ybuf + (long)p1 * DMODEL + t * 4);
  float v0 = xv.x + s0 * b2f(y0.x) + s1 * b2f(y1.x);
  float v1 = xv.y + s0 * b2f(y0.y) + s1 * b2f(y1.y);
  float v2 = xv.z + s0 * b2f(y0.z) + s1 * b2f(y1.z);
  float v3 = xv.w + s0 * b2f(y0.w) + s1 * b2f(y1.w);
  float s = block_sum(v0 + v1 + v2 + v3, red);
  float mean = s * (1.0f / DMODEL);
  float d0 = v0 - mean, d1 = v1 - mean, d2 = v2 - mean, d3 = v3 - mean;
  float sq = block_sum(d0 * d0 + d1 * d1 + d2 * d2 + d3 * d3, red);
  float rstd = rsqrtf(sq * (1.0f / DMODEL) + 1e-5f);
  float4 gg = *(const float4*)(g + t * 4);
  float4 bv = *(const float4*)(bb + t * 4);
  float4 of;
  of.x = d0 * rstd * gg.x + bv.x; of.y = d1 * rstd * gg.y + bv.y;
  of.z = d2 * rstd * gg.z + bv.z; of.w = d3 * rstd * gg.w + bv.w;
  *(float4*)(outp + row * DMODEL + t * 4) = of;
}

// --------------------------------- launch ----------------------------------

extern "C" void kernel_launch(void* const* d_in, const int* in_sizes, int n_in,
                              void* d_out, int out_size, void* d_ws, size_t ws_size,
                              hipStream_t stream) {
  (void)in_sizes; (void)n_in; (void)out_size;
  const float* x    = (const float*)d_in[0];
  const float* Wq   = (const float*)d_in[1];
  const float* bq   = (const float*)d_in[2];
  const float* Wk   = (const float*)d_in[3];
  const float* bk   = (const float*)d_in[4];
  const float* Wv   = (const float*)d_in[5];
  const float* bv   = (const float*)d_in[6];
  const float* Wo   = (const float*)d_in[7];
  const float* bo   = (const float*)d_in[8];
  const float* ln1g = (const float*)d_in[9];
  const float* ln1b = (const float*)d_in[10];
  const float* gw   = (const float*)d_in[11];
  const float* gb   = (const float*)d_in[12];
  const float* W1   = (const float*)d_in[13];
  const float* b1   = (const float*)d_in[14];
  const float* W2   = (const float*)d_in[15];
  const float* b2   = (const float*)d_in[16];
  const float* ln3g = (const float*)d_in[17];
  const float* ln3b = (const float*)d_in[18];
  float* outp = (float*)d_out;

  char* ws = (char*)d_ws;
  size_t o = 0;
  auto alloc = [&](size_t b) { size_t r = o; o = (o + b + 255) & ~(size_t)255; return r; };
  const long T = T_TOK, D = DMODEL, F = DFF;
  size_t wqT_o = alloc(D * D * 2), wkT_o = alloc(D * D * 2);
  size_t wvT_o = alloc(D * D * 2), woT_o = alloc(D * D * 2);
  size_t w1T_o = alloc((size_t)NEXP * D * F * 2);
  size_t w2T_o = alloc((size_t)NEXP * D * F * 2);
  size_t xb_o  = alloc(T * D * 2);
  size_t x1f_o = alloc(T * D * 4);
  size_t x1b_o = alloc(T * D * 2);
  size_t yb_o  = alloc((size_t)NSLOT * D * 2);
  size_t ab_o  = alloc((size_t)NSLOT_PAD * F * 2);
  size_t cnt_o = alloc(64);              // cnt[8] | fill[8]
  size_t off_o = alloc(64);
  size_t nmb_o = alloc(16);
  size_t tabe_o = alloc(80 * 4), tabr_o = alloc(80 * 4), tabn_o = alloc(80 * 4);
  size_t t2i_o = alloc((size_t)NSLOT * 4), t2s_o = alloc((size_t)NSLOT * 4);
  size_t st_o = alloc((size_t)NSLOT * 4), ss_o = alloc((size_t)NSLOT * 4);
  size_t pos_o = alloc((size_t)NSLOT * 4);
  if (o > ws_size) return;  // insufficient workspace: fail cleanly

  ushort* wqT = (ushort*)(ws + wqT_o); ushort* wkT = (ushort*)(ws + wkT_o);
  ushort* wvT = (ushort*)(ws + wvT_o); ushort* woT = (ushort*)(ws + woT_o);
  ushort* w1T = (ushort*)(ws + w1T_o); ushort* w2T = (ushort*)(ws + w2T_o);
  ushort* xb  = (ushort*)(ws + xb_o);
  float*  x1f = (float*)(ws + x1f_o);
  ushort* x1b = (ushort*)(ws + x1b_o);
  ushort* ybuf = (ushort*)(ws + yb_o);
  ushort* abuf = (ushort*)(ws + ab_o);
  // attention sub-buffers live inside abuf (dead before MoE GEMMs run)
  ushort* qb = abuf;
  ushort* kb = qb + T * D;
  ushort* vb = kb + T * D;
  ushort* vt = vb + T * D;
  ushort* ctx = vt + T * D;
  int* cnt = (int*)(ws + cnt_o); int* fill = cnt + 8;
  int* offe = (int*)(ws + off_o);
  int* nmb = (int*)(ws + nmb_o);
  int* tab_e = (int*)(ws + tabe_o); int* tab_r0 = (int*)(ws + tabr_o);
  int* tab_end = (int*)(ws + tabn_o);
  int* top2i = (int*)(ws + t2i_o); float* top2s = (float*)(ws + t2s_o);
  int* slot_token = (int*)(ws + st_o); float* slot_scale = (float*)(ws + ss_o);
  int* pos = (int*)(ws + pos_o);

  // 1. x -> bf16 (also zeroes routing counters in block 0)
  hipLaunchKernelGGL(cvt_bf16, dim3((T * D) / 1024), dim3(256), 0, stream, x, xb, T * D, cnt);
  // 2. weight transposes (fp32 -> bf16 [N][K])
  hipLaunchKernelGGL(wtrans, dim3(16, 16, 1), dim3(256), 0, stream, Wq, wqT, (int)D, (int)D);
  hipLaunchKernelGGL(wtrans, dim3(16, 16, 1), dim3(256), 0, stream, Wk, wkT, (int)D, (int)D);
  hipLaunchKernelGGL(wtrans, dim3(16, 16, 1), dim3(256), 0, stream, Wv, wvT, (int)D, (int)D);
  hipLaunchKernelGGL(wtrans, dim3(16, 16, 1), dim3(256), 0, stream, Wo, woT, (int)D, (int)D);
  hipLaunchKernelGGL(wtrans, dim3(64, 16, 8), dim3(256), 0, stream, W1, w1T, (int)D, (int)F);
  hipLaunchKernelGGL(wtrans, dim3(16, 64, 8), dim3(256), 0, stream, W2, w2T, (int)F, (int)D);
  // 3. QKV projections (Q folds 0.125); grid (n,m,z) for XCD locality
  hipLaunchKernelGGL(gemm_qkv, dim3(8, 32, 3), dim3(256), 0, stream,
                     xb, wqT, wkT, wvT, bq, bk, bv, qb, kb, vb);
  // 4. V -> Vt [bh][d][s]
  hipLaunchKernelGGL(vtrans, dim3(32, 16, 2), dim3(256), 0, stream, vb, vt);
  // 5. flash attention -> ctx  (64-row q tiles, 4 blocks/CU)
  hipLaunchKernelGGL(flash_attn, dim3(32, 32), dim3(256), 0, stream, qb, kb, vt, ctx);
  // 6. O projection + residual -> x1f (pre-LN); global_load_lds probe
  hipLaunchKernelGGL(gemm_oproj, dim3(8, 32), dim3(256), 0, stream, ctx, woT, bo, x, x1f);
  // 7. LN1 + gate + top2 + counts (fused)
  hipLaunchKernelGGL(ln1_gate, dim3(T), dim3(256), 0, stream,
                     x1f, ln1g, ln1b, gw, gb, x1f, x1b, top2i, top2s, cnt);
  // 8. routing tables (128-row groups)
  hipLaunchKernelGGL(build_tables, dim3(1), dim3(64), 0, stream, cnt, offe, tab_e, tab_r0, tab_end, nmb);
  hipLaunchKernelGGL(scatter_slots, dim3(T / 256), dim3(256), 0, stream,
                     top2i, top2s, offe, fill, slot_token, slot_scale, pos);
  // 9. MoE expert GEMMs (grouped, 128-row tiles, worst-case 72 m-blocks)
  hipLaunchKernelGGL(gemm_moe, dim3(32, 72), dim3(256), 0, stream,
                     2, x1b, slot_token, w1T, b1, abuf, (int)D, (int)F,
                     tab_e, tab_r0, tab_end, nmb);
  hipLaunchKernelGGL(gemm_moe, dim3(8, 72), dim3(256), 0, stream,
                     3, abuf, slot_token, w2T, b2, ybuf, (int)F, (int)D,
                     tab_e, tab_r0, tab_end, nmb);
  // 10. combine + LN3 -> out
  hipLaunchKernelGGL(combine_ln3, dim3(T), dim3(256), 0, stream,
                     x1f, ybuf, pos, slot_scale, ln3g, ln3b, outp);
}